// Round 11
// baseline (487.790 us; speedup 1.0000x reference)
//
#include <hip/hip_runtime.h>
#include <hip/hip_bf16.h>

// LayoutLM w/ visual features — split-bf16 via VIRTUAL-K MFMA GEMM,
// counted-vmcnt deep pipeline (T3+T4+T5+T1).
// B=64 S=512 H=768 R=256 VD=256 NC=9
// fuse: [16384,1024]@[1024,768] as virtual K'=3072 bf16 GEMM
// h1:   [16384,768]@[768,512]  as virtual K'=2304
// Virtual seg s: A-src = {Ah,Ah,Al}[s], B-src = {Bh,Bl,Bh}[s]; all segs
// accumulate into the same fp32 acc => exactly the 3-term split product.
// ws layout identical to R8/R9 (~123 MB).

#define Bb 64
#define Ss 512
#define Hh 768
#define Rr 256
#define VDd 256
#define NCc 9

typedef __attribute__((ext_vector_type(8))) short short8v;  // 8 bf16
typedef __attribute__((ext_vector_type(4))) float f32x4;

static __device__ __forceinline__ unsigned short f2bf(float v) {
    __hip_bfloat16 b = __float2bfloat16(v);
    return __builtin_bit_cast(unsigned short, b);
}
static __device__ __forceinline__ float bf2f(unsigned short u) {
    return __bfloat162float(__builtin_bit_cast(__hip_bfloat16, u));
}
static __device__ __forceinline__ void gll16(const void* g, void* l) {
    __builtin_amdgcn_global_load_lds(
        (const __attribute__((address_space(1))) void*)g,
        (__attribute__((address_space(3))) void*)l, 16, 0, 0);
}

// ---------------- Weq / beq precompute (fp32) ----------------
__global__ __launch_bounds__(768) void weq_beq_kernel(
    const float* __restrict__ Wp, const float* __restrict__ bp,
    const float* __restrict__ Wf, const float* __restrict__ bf,
    float* __restrict__ Weq, float* __restrict__ beq)
{
    int n = threadIdx.x;
    int m = blockIdx.x;
    const float* Wfv = Wf + 768 * 768 + n;
    float acc = 0.f;
    if (m < 256) {
        const float* a = Wp + m * 768;
        #pragma unroll 4
        for (int k = 0; k < 768; ++k) acc += a[k] * Wfv[(size_t)k * 768];
        Weq[m * 768 + n] = acc;
    } else {
        #pragma unroll 4
        for (int k = 0; k < 768; ++k) acc += bp[k] * Wfv[(size_t)k * 768];
        beq[n] = bf[n] + acc;
    }
}

// ------- sparse masked mean pool + feats pack -> A_cat bf16 hi/lo -------
__global__ __launch_bounds__(256) void pool_kernel(
    const float* __restrict__ seq,   // [B,S,H]
    const float* __restrict__ roi,   // [B,R,4]
    const int*   __restrict__ bbox,  // [B,S,4]
    const int*   __restrict__ amask, // [B,S]
    const float* __restrict__ feats, // [B*R,256]
    unsigned short* __restrict__ ah, // A_hi [16384][1024]
    unsigned short* __restrict__ al)
{
    int br = blockIdx.x;
    int b  = br >> 8;
    int tid = threadIdx.x;
    int wave = tid >> 6, lane = tid & 63;

    float4 rb = reinterpret_cast<const float4*>(roi)[br];

    __shared__ unsigned long long wm[8];
    __shared__ int s_idx[Ss];

    const int4* bb4 = reinterpret_cast<const int4*>(bbox) + (size_t)b * Ss;
    const int*  am  = amask + (size_t)b * Ss;

    for (int it = 0; it < 2; ++it) {
        int s = it * 256 + tid;
        bool pred = false;
        if (s >= 1 && am[s] == 1) {
            int4 tb = bb4[s];
            pred = ((float)tb.x >= rb.x) && ((float)tb.z <= rb.z) &&
                   ((float)tb.y >= rb.y) && ((float)tb.w <= rb.w);
        }
        unsigned long long mk = __ballot(pred);
        if (lane == 0) wm[it * 4 + wave] = mk;
    }
    __syncthreads();

    int pre[8]; int tot = 0;
    #pragma unroll
    for (int c = 0; c < 8; ++c) { pre[c] = tot; tot += __popcll(wm[c]); }

    #pragma unroll
    for (int it = 0; it < 2; ++it) {
        int c = it * 4 + wave;
        unsigned long long mk = wm[c];
        if ((mk >> lane) & 1ull) {
            int pos = pre[c] + __popcll(mk & ((1ull << lane) - 1ull));
            s_idx[pos] = c * 64 + lane;
        }
    }
    __syncthreads();

    float a0 = 0.f, a1 = 0.f, a2 = 0.f;
    for (int i = 0; i < tot; ++i) {
        const float* row = seq + ((size_t)b * Ss + s_idx[i]) * Hh;
        a0 += row[tid];
        a1 += row[tid + 256];
        a2 += row[tid + 512];
    }
    float inv = 1.f / fmaxf((float)tot, 1.f);
    a0 *= inv; a1 *= inv; a2 *= inv;

    size_t o = (size_t)br * 1024;
    unsigned short h0 = f2bf(a0), h1 = f2bf(a1), h2 = f2bf(a2);
    ah[o + tid]       = h0;  al[o + tid]       = f2bf(a0 - bf2f(h0));
    ah[o + tid + 256] = h1;  al[o + tid + 256] = f2bf(a1 - bf2f(h1));
    ah[o + tid + 512] = h2;  al[o + tid + 512] = f2bf(a2 - bf2f(h2));
    // feats -> cols 768..1023 (merged feats_conv)
    float fv = feats[(size_t)br * VDd + tid];
    unsigned short fh = f2bf(fv);
    ah[o + 768 + tid] = fh;
    al[o + 768 + tid] = f2bf(fv - bf2f(fh));
}

// ------- transpose + split-convert: dst[n][co+k] = src[k][n] -------
__global__ __launch_bounds__(256) void tconv_kernel(
    const float* __restrict__ src, int Ns,
    unsigned short* __restrict__ dh, unsigned short* __restrict__ dl,
    int ldd, int co)
{
    __shared__ float t[32][33];
    int k0 = blockIdx.x * 32, n0 = blockIdx.y * 32;
    int tx = threadIdx.x & 31, ty = threadIdx.x >> 5;
    #pragma unroll
    for (int i = 0; i < 4; ++i)
        t[ty + i * 8][tx] = src[(size_t)(k0 + ty + i * 8) * Ns + n0 + tx];
    __syncthreads();
    #pragma unroll
    for (int i = 0; i < 4; ++i) {
        int n = n0 + ty + i * 8;
        int k = k0 + tx;
        float v = t[tx][ty + i * 8];
        size_t o = (size_t)n * ldd + co + k;
        unsigned short h = f2bf(v);
        dh[o] = h;
        dl[o] = f2bf(v - bf2f(h));
    }
}

// ---------------- virtual-K split-bf16 GEMM, counted-vmcnt pipeline ------
// BM = FM*32 (128 or 256), BN = 256, virtual K-tile = 32.
// 512 thr = 8 waves (2M x 4N); per-wave C: FM*16 x 64 -> acc[FM][4].
// LDS: 4 rotating buffers x (A[BM][32] | B[256][32]) bf16, XOR chunk-swizzle
// (involution: staged pre-swizzled source, swizzled ds_read).
// Pipeline: stage 2 tiles ahead; steady-state wait = vmcnt(2L) (L loads/tile)
// fused with s_barrier in ONE asm blob ("memory" clobber pins ds_reads).
template<int FM>
__global__ __launch_bounds__(512) void gemm8p(
    const unsigned short* __restrict__ Ah, const unsigned short* __restrict__ Al, int lda,
    const unsigned short* __restrict__ Bh, const unsigned short* __restrict__ Bl, int ldb,
    int K, const float* __restrict__ bias, int epi,
    unsigned short* __restrict__ Ch, unsigned short* __restrict__ Cl,
    float* __restrict__ Cf, int ldc)
{
    constexpr int BM  = FM * 32;        // 128 or 256
    constexpr int ACH = BM / 16;        // A 1KB-chunks per tile (8 or 16)
    constexpr int AIN = ACH / 8;        // A gll16 per wave (1 or 2)
    constexpr int ASZ = BM * 64;        // A tile bytes
    constexpr int BUF = ASZ + 16384;    // per-buffer bytes
    __shared__ __align__(16) unsigned char lds[4 * BUF];   // 96KB / 128KB

    const int tid  = threadIdx.x;
    const int w    = tid >> 6, lane = tid & 63;
    const int wm   = w >> 2, wn = w & 3;
    const int fr   = lane & 15, kg = lane >> 4;
    const int rsub = lane >> 2, cd = lane & 3;

    // XCD-bijective swizzle (nwg % 8 == 0 at both call sites)
    const int gx   = gridDim.x;
    const int nwg  = gx * gridDim.y;
    const int cpx  = nwg >> 3;
    const int orig = blockIdx.y * gx + blockIdx.x;
    const int swz  = (orig & 7) * cpx + (orig >> 3);
    const int m0   = (swz / gx) * BM;
    const int n0   = (swz % gx) * 256;

    const int TPS = K >> 5;            // physical tiles per segment
    const int NT  = 3 * TPS;           // virtual tiles

    // rolling stage state: seg, k-offset, buffer
    int st_seg = 0, st_kp = 0, st_buf = 0;
    auto STAGE = [&]() {
        const unsigned short* As = (st_seg == 2) ? Al : Ah;
        const unsigned short* Bs = (st_seg == 1) ? Bl : Bh;
        unsigned char* base = lds + st_buf * BUF;
        #pragma unroll
        for (int i = 0; i < AIN; ++i) {
            int cc = w * AIN + i;
            int r  = cc * 16 + rsub;
            int cs = cd ^ ((r >> 1) & 3);
            gll16(As + (size_t)(m0 + r) * lda + st_kp + cs * 8,
                  base + cc * 1024 + lane * 16);
        }
        #pragma unroll
        for (int i = 0; i < 2; ++i) {
            int cc = w * 2 + i;
            int r  = cc * 16 + rsub;
            int cs = cd ^ ((r >> 1) & 3);
            gll16(Bs + (size_t)(n0 + r) * ldb + st_kp + cs * 8,
                  base + ASZ + cc * 1024 + lane * 16);
        }
        st_kp += 32;
        if (st_kp >= K) { st_kp = 0; ++st_seg; }
        st_buf = (st_buf + 1) & 3;
    };

    f32x4 acc[FM][4] = {};

    STAGE(); STAGE(); STAGE();          // tiles 0,1,2 in flight

    for (int t = 0; t < NT; ++t) {
        // top-of-tile: ensure tile t landed (all waves), without draining the
        // 2 newest tiles' loads. Single asm blob: waitcnt + barrier.
        if (t < NT - 2) {
            if constexpr (FM == 8)
                asm volatile("s_waitcnt vmcnt(8)\n\ts_barrier" ::: "memory");
            else
                asm volatile("s_waitcnt vmcnt(6)\n\ts_barrier" ::: "memory");
        } else {
            asm volatile("s_waitcnt vmcnt(0)\n\ts_barrier" ::: "memory");
        }
        if (t + 3 < NT) STAGE();        // into buf[(t+3)&3] == just-freed slot

        const unsigned char* bufA = lds + (t & 3) * BUF;
        const unsigned char* bufB = bufA + ASZ;

        short8v bfrag[4];
        #pragma unroll
        for (int fn = 0; fn < 4; ++fn) {
            int br = wn * 64 + fn * 16 + fr;
            bfrag[fn] = *(const short8v*)(bufB + br * 64 + ((kg ^ ((br >> 1) & 3)) << 4));
        }
        #pragma unroll
        for (int ph = 0; ph < FM / 4; ++ph) {
            if (ph) asm volatile("s_barrier" ::: "memory");   // phase lockstep
            short8v afrag[4];
            #pragma unroll
            for (int q = 0; q < 4; ++q) {
                int ar = wm * (FM * 16) + (ph * 4 + q) * 16 + fr;
                afrag[q] = *(const short8v*)(bufA + ar * 64 + ((kg ^ ((ar >> 1) & 3)) << 4));
            }
            __builtin_amdgcn_s_setprio(1);
            #pragma unroll
            for (int q = 0; q < 4; ++q)
                #pragma unroll
                for (int fn = 0; fn < 4; ++fn)
                    acc[ph * 4 + q][fn] = __builtin_amdgcn_mfma_f32_16x16x32_bf16(
                        afrag[q], bfrag[fn], acc[ph * 4 + q][fn], 0, 0, 0);
            __builtin_amdgcn_s_setprio(0);
        }
    }

    // epilogue: C/D layout col = lane&15, row = kg*4 + j
    #pragma unroll
    for (int fn = 0; fn < 4; ++fn) {
        int col = n0 + wn * 64 + fn * 16 + fr;
        float bv = bias[col];
        #pragma unroll
        for (int fm = 0; fm < FM; ++fm) {
            int rowb = m0 + wm * (FM * 16) + fm * 16 + kg * 4;
            #pragma unroll
            for (int j = 0; j < 4; ++j) {
                float v = fmaxf(acc[fm][fn][j] + bv, 0.f);
                size_t o = (size_t)(rowb + j) * ldc + col;
                if (epi) {
                    unsigned short h = f2bf(v);
                    Ch[o] = h;
                    Cl[o] = f2bf(v - bf2f(h));
                } else {
                    Cf[o] = v;
                }
            }
        }
    }
}

// ---------------- logits: out = h @ W2 + b2, K=512, N=9 ----------------
__global__ __launch_bounds__(256) void logits_kernel(
    const float* __restrict__ h, const float* __restrict__ W2,
    const float* __restrict__ b2, float* __restrict__ out)
{
    __shared__ float w2s[512 * NCc];
    for (int i = threadIdx.x; i < 512 * NCc; i += 256) w2s[i] = W2[i];
    __syncthreads();

    int wave = threadIdx.x >> 6, lane = threadIdx.x & 63;
    int row = blockIdx.x * 4 + wave;
    const float* hr = h + (size_t)row * 512;

    float p[NCc] = {};
    #pragma unroll
    for (int j = 0; j < 8; ++j) {
        int k = lane + 64 * j;
        float hv = hr[k];
        const float* wrow = &w2s[k * NCc];
        #pragma unroll
        for (int n = 0; n < NCc; ++n) p[n] += hv * wrow[n];
    }
    #pragma unroll
    for (int off = 32; off > 0; off >>= 1) {
        #pragma unroll
        for (int n = 0; n < NCc; ++n) p[n] += __shfl_down(p[n], off);
    }
    if (lane == 0) {
        float* orow = out + (size_t)row * NCc;
        #pragma unroll
        for (int n = 0; n < NCc; ++n) orow[n] = p[n] + b2[n];
    }
}

extern "C" void kernel_launch(void* const* d_in, const int* in_sizes, int n_in,
                              void* d_out, int out_size, void* d_ws, size_t ws_size,
                              hipStream_t stream)
{
    const float* seq   = (const float*)d_in[0];
    const float* feats = (const float*)d_in[1];
    const float* roi   = (const float*)d_in[2];
    const int*   bbox  = (const int*)d_in[3];
    const int*   amask = (const int*)d_in[4];
    const float* Wp = (const float*)d_in[5];
    const float* bp = (const float*)d_in[6];
    const float* Wf = (const float*)d_in[7];
    const float* bf = (const float*)d_in[8];
    const float* W1 = (const float*)d_in[9];
    const float* b1 = (const float*)d_in[10];
    const float* W2 = (const float*)d_in[11];
    const float* b2 = (const float*)d_in[12];
    float* out = (float*)d_out;

    char* ws = (char*)d_ws;
    unsigned short* A_hi  = (unsigned short*)(ws);
    unsigned short* A_lo  = (unsigned short*)(ws + 33554432);
    unsigned short* fu_hi = (unsigned short*)(ws + 67108864);
    unsigned short* fu_lo = (unsigned short*)(ws + 92274688);
    unsigned short* Bf_hi = (unsigned short*)(ws + 117440512);
    unsigned short* Bf_lo = (unsigned short*)(ws + 119013376);
    unsigned short* B1_hi = (unsigned short*)(ws + 120586240);
    unsigned short* B1_lo = (unsigned short*)(ws + 121372672);
    float*          Weq   = (float*)(ws + 122159104);
    float*          beq   = (float*)(ws + 122945536);
    float*          hbuf  = (float*)(ws);              // aliases A_hi/A_lo (dead after fuse)

    weq_beq_kernel<<<257, 768, 0, stream>>>(Wp, bp, Wf, bf, Weq, beq);
    pool_kernel<<<Bb * Rr, 256, 0, stream>>>(seq, roi, bbox, amask, feats, A_hi, A_lo);
    // Bf[768][1024] = [ Wf_t^T | Weq^T ]
    tconv_kernel<<<dim3(24, 24), 256, 0, stream>>>(Wf, 768, Bf_hi, Bf_lo, 1024, 0);
    tconv_kernel<<<dim3(8, 24), 256, 0, stream>>>(Weq, 768, Bf_hi, Bf_lo, 1024, 768);
    // B1[512][768] = W1^T
    tconv_kernel<<<dim3(24, 16), 256, 0, stream>>>(W1, 512, B1_hi, B1_lo, 768, 0);

    // fused = relu(A_cat @ B_cat + beq): BM=256, grid 3x64 = 192 (%8==0)
    gemm8p<8><<<dim3(768 / 256, 16384 / 256), 512, 0, stream>>>(
        A_hi, A_lo, 1024, Bf_hi, Bf_lo, 1024, 1024, beq, 1,
        fu_hi, fu_lo, nullptr, 768);
    // h = relu(fused @ W1 + b1): BM=128, grid 2x128 = 256 (%8==0, full chip)
    gemm8p<4><<<dim3(512 / 256, 16384 / 128), 512, 0, stream>>>(
        fu_hi, fu_lo, 768, B1_hi, B1_lo, 768, 768, b1, 0,
        nullptr, nullptr, hbuf, 512);

    logits_kernel<<<(Bb * Rr) / 4, 256, 0, stream>>>(hbuf, W2, b2, out);
}

// Round 12
// 478.380 us; speedup vs baseline: 1.0197x; 1.0197x over previous
//
#include <hip/hip_runtime.h>
#include <hip/hip_bf16.h>

// LayoutLM w/ visual features — split-bf16 via VIRTUAL-K MFMA GEMM.
// R12: counted-vmcnt pipeline with COMPILE-TIME LDS buffer indices
// (4x unrolled tile loop so alias analysis can prove stage/read disjoint;
// without this the compiler conservatively drains vmcnt before each
// ds_read batch, serializing the pipeline — R9/R11 both hit that wall).
// B=64 S=512 H=768 R=256 VD=256 NC=9
// fuse: [16384,1024]@[1024,768] as virtual K'=3072;  h1: K'=2304.
// Virtual seg s: A-src={Ah,Ah,Al}[s], B-src={Bh,Bl,Bh}[s]; one fp32 acc.

#define Bb 64
#define Ss 512
#define Hh 768
#define Rr 256
#define VDd 256
#define NCc 9

typedef __attribute__((ext_vector_type(8))) short short8v;  // 8 bf16
typedef __attribute__((ext_vector_type(4))) float f32x4;

static __device__ __forceinline__ unsigned short f2bf(float v) {
    __hip_bfloat16 b = __float2bfloat16(v);
    return __builtin_bit_cast(unsigned short, b);
}
static __device__ __forceinline__ float bf2f(unsigned short u) {
    return __bfloat162float(__builtin_bit_cast(__hip_bfloat16, u));
}
static __device__ __forceinline__ void gll16(const void* g, void* l) {
    __builtin_amdgcn_global_load_lds(
        (const __attribute__((address_space(1))) void*)g,
        (__attribute__((address_space(3))) void*)l, 16, 0, 0);
}

// ---------------- Weq / beq precompute (fp32) ----------------
__global__ __launch_bounds__(768) void weq_beq_kernel(
    const float* __restrict__ Wp, const float* __restrict__ bp,
    const float* __restrict__ Wf, const float* __restrict__ bf,
    float* __restrict__ Weq, float* __restrict__ beq)
{
    int n = threadIdx.x;
    int m = blockIdx.x;
    const float* Wfv = Wf + 768 * 768 + n;
    float acc = 0.f;
    if (m < 256) {
        const float* a = Wp + m * 768;
        #pragma unroll 4
        for (int k = 0; k < 768; ++k) acc += a[k] * Wfv[(size_t)k * 768];
        Weq[m * 768 + n] = acc;
    } else {
        #pragma unroll 4
        for (int k = 0; k < 768; ++k) acc += bp[k] * Wfv[(size_t)k * 768];
        beq[n] = bf[n] + acc;
    }
}

// ------- sparse masked mean pool + feats pack -> A_cat bf16 hi/lo -------
__global__ __launch_bounds__(256) void pool_kernel(
    const float* __restrict__ seq,   // [B,S,H]
    const float* __restrict__ roi,   // [B,R,4]
    const int*   __restrict__ bbox,  // [B,S,4]
    const int*   __restrict__ amask, // [B,S]
    const float* __restrict__ feats, // [B*R,256]
    unsigned short* __restrict__ ah, // A_hi [16384][1024]
    unsigned short* __restrict__ al)
{
    int br = blockIdx.x;
    int b  = br >> 8;
    int tid = threadIdx.x;
    int wave = tid >> 6, lane = tid & 63;

    float4 rb = reinterpret_cast<const float4*>(roi)[br];

    __shared__ unsigned long long wm[8];
    __shared__ int s_idx[Ss];

    const int4* bb4 = reinterpret_cast<const int4*>(bbox) + (size_t)b * Ss;
    const int*  am  = amask + (size_t)b * Ss;

    for (int it = 0; it < 2; ++it) {
        int s = it * 256 + tid;
        bool pred = false;
        if (s >= 1 && am[s] == 1) {
            int4 tb = bb4[s];
            pred = ((float)tb.x >= rb.x) && ((float)tb.z <= rb.z) &&
                   ((float)tb.y >= rb.y) && ((float)tb.w <= rb.w);
        }
        unsigned long long mk = __ballot(pred);
        if (lane == 0) wm[it * 4 + wave] = mk;
    }
    __syncthreads();

    int pre[8]; int tot = 0;
    #pragma unroll
    for (int c = 0; c < 8; ++c) { pre[c] = tot; tot += __popcll(wm[c]); }

    #pragma unroll
    for (int it = 0; it < 2; ++it) {
        int c = it * 4 + wave;
        unsigned long long mk = wm[c];
        if ((mk >> lane) & 1ull) {
            int pos = pre[c] + __popcll(mk & ((1ull << lane) - 1ull));
            s_idx[pos] = c * 64 + lane;
        }
    }
    __syncthreads();

    float a0 = 0.f, a1 = 0.f, a2 = 0.f;
    for (int i = 0; i < tot; ++i) {
        const float* row = seq + ((size_t)b * Ss + s_idx[i]) * Hh;
        a0 += row[tid];
        a1 += row[tid + 256];
        a2 += row[tid + 512];
    }
    float inv = 1.f / fmaxf((float)tot, 1.f);
    a0 *= inv; a1 *= inv; a2 *= inv;

    size_t o = (size_t)br * 1024;
    unsigned short h0 = f2bf(a0), h1 = f2bf(a1), h2 = f2bf(a2);
    ah[o + tid]       = h0;  al[o + tid]       = f2bf(a0 - bf2f(h0));
    ah[o + tid + 256] = h1;  al[o + tid + 256] = f2bf(a1 - bf2f(h1));
    ah[o + tid + 512] = h2;  al[o + tid + 512] = f2bf(a2 - bf2f(h2));
    // feats -> cols 768..1023 (merged feats_conv)
    float fv = feats[(size_t)br * VDd + tid];
    unsigned short fh = f2bf(fv);
    ah[o + 768 + tid] = fh;
    al[o + 768 + tid] = f2bf(fv - bf2f(fh));
}

// ------- transpose + split-convert: dst[n][co+k] = src[k][n] -------
__global__ __launch_bounds__(256) void tconv_kernel(
    const float* __restrict__ src, int Ns,
    unsigned short* __restrict__ dh, unsigned short* __restrict__ dl,
    int ldd, int co)
{
    __shared__ float t[32][33];
    int k0 = blockIdx.x * 32, n0 = blockIdx.y * 32;
    int tx = threadIdx.x & 31, ty = threadIdx.x >> 5;
    #pragma unroll
    for (int i = 0; i < 4; ++i)
        t[ty + i * 8][tx] = src[(size_t)(k0 + ty + i * 8) * Ns + n0 + tx];
    __syncthreads();
    #pragma unroll
    for (int i = 0; i < 4; ++i) {
        int n = n0 + ty + i * 8;
        int k = k0 + tx;
        float v = t[tx][ty + i * 8];
        size_t o = (size_t)n * ldd + co + k;
        unsigned short h = f2bf(v);
        dh[o] = h;
        dl[o] = f2bf(v - bf2f(h));
    }
}

// ---------------- virtual-K split-bf16 GEMM, counted-vmcnt pipeline ------
// BM = FM*32, BN = 256, 512 thr = 8 waves (2M x 4N), K-tile 32.
// 4 rotating LDS buffers; tile loop unrolled 4x so every buffer offset is a
// compile-time literal (stage target (u+3)&3, read buffer u) -> alias
// analysis proves disjointness -> no conservative vmcnt drain before reads.
// Steady-state wait: vmcnt(2 newest tiles' loads) + raw s_barrier.
template<int FM>
__global__ __launch_bounds__(512) void gemm8p(
    const unsigned short* __restrict__ Ah, const unsigned short* __restrict__ Al, int lda,
    const unsigned short* __restrict__ Bh, const unsigned short* __restrict__ Bl, int ldb,
    int K, const float* __restrict__ bias, int epi,
    unsigned short* __restrict__ Ch, unsigned short* __restrict__ Cl,
    float* __restrict__ Cf, int ldc)
{
    constexpr int BM  = FM * 32;        // 128 or 256
    constexpr int AIN = BM / 128;       // A gll16 per wave (1 or 2)
    constexpr int ASZ = BM * 64;        // A tile bytes
    constexpr int BUF = ASZ + 16384;    // per-buffer bytes
    __shared__ __align__(16) unsigned char lds[4 * BUF];   // 96KB / 128KB

    const int tid  = threadIdx.x;
    const int w    = tid >> 6, lane = tid & 63;
    const int wm   = w >> 2, wn = w & 3;
    const int fr   = lane & 15, kg = lane >> 4;
    const int rsub = lane >> 2, cd = lane & 3;

    // XCD-bijective swizzle (nwg % 8 == 0 at both call sites)
    const int gx   = gridDim.x;
    const int nwg  = gx * gridDim.y;
    const int cpx  = nwg >> 3;
    const int orig = blockIdx.y * gx + blockIdx.x;
    const int swz  = (orig & 7) * cpx + (orig >> 3);
    const int m0   = (swz / gx) * BM;
    const int n0   = (swz % gx) * 256;

    const int TPS = K >> 5;            // physical tiles per segment
    const int NT  = 3 * TPS;           // virtual tiles (96 or 72; %4==0)

    int st_seg = 0, st_kp = 0;         // rolling stage cursor
    auto STAGE = [&](int bufc) {       // bufc is a literal at every call site
        const unsigned short* As = (st_seg == 2) ? Al : Ah;
        const unsigned short* Bs = (st_seg == 1) ? Bl : Bh;
        unsigned char* base = lds + bufc * BUF;
        #pragma unroll
        for (int i = 0; i < AIN; ++i) {
            int cc = w * AIN + i;
            int r  = cc * 16 + rsub;
            int cs = cd ^ ((r >> 1) & 3);
            gll16(As + (size_t)(m0 + r) * lda + st_kp + cs * 8,
                  base + cc * 1024 + lane * 16);
        }
        #pragma unroll
        for (int i = 0; i < 2; ++i) {
            int cc = w * 2 + i;
            int r  = cc * 16 + rsub;
            int cs = cd ^ ((r >> 1) & 3);
            gll16(Bs + (size_t)(n0 + r) * ldb + st_kp + cs * 8,
                  base + ASZ + cc * 1024 + lane * 16);
        }
        st_kp += 32;
        if (st_kp >= K) { st_kp = 0; ++st_seg; }
    };

    f32x4 acc[FM][4] = {};

    STAGE(0); STAGE(1); STAGE(2);      // tiles 0,1,2 in flight

    for (int t0 = 0; t0 < NT; t0 += 4) {
        #pragma unroll
        for (int u = 0; u < 4; ++u) {
            const int t = t0 + u;      // t & 3 == u (t0 multiple of 4)
            // wait for tile t's loads (4 or 3 per wave), keep 2 newest tiles
            // in flight; collective via raw barrier (no implicit drain).
            if (t < NT - 2) {
                if constexpr (FM == 8)
                    asm volatile("s_waitcnt vmcnt(8)" ::: "memory");
                else
                    asm volatile("s_waitcnt vmcnt(6)" ::: "memory");
            } else {
                asm volatile("s_waitcnt vmcnt(0)" ::: "memory");
            }
            __builtin_amdgcn_s_barrier();
            if (t + 3 < NT) STAGE((u + 3) & 3);   // literal buffer index

            const unsigned char* bufA = lds + u * BUF;      // literal
            const unsigned char* bufB = bufA + ASZ;

            short8v bfrag[4];
            #pragma unroll
            for (int fn = 0; fn < 4; ++fn) {
                int br = wn * 64 + fn * 16 + fr;
                bfrag[fn] = *(const short8v*)(bufB + br * 64 + ((kg ^ ((br >> 1) & 3)) << 4));
            }
            #pragma unroll
            for (int ph = 0; ph < FM / 4; ++ph) {
                if (ph) __builtin_amdgcn_s_barrier();       // phase lockstep
                short8v afrag[4];
                #pragma unroll
                for (int q = 0; q < 4; ++q) {
                    int ar = wm * (FM * 16) + (ph * 4 + q) * 16 + fr;
                    afrag[q] = *(const short8v*)(bufA + ar * 64 + ((kg ^ ((ar >> 1) & 3)) << 4));
                }
                __builtin_amdgcn_s_setprio(1);
                #pragma unroll
                for (int q = 0; q < 4; ++q)
                    #pragma unroll
                    for (int fn = 0; fn < 4; ++fn)
                        acc[ph * 4 + q][fn] = __builtin_amdgcn_mfma_f32_16x16x32_bf16(
                            afrag[q], bfrag[fn], acc[ph * 4 + q][fn], 0, 0, 0);
                __builtin_amdgcn_s_setprio(0);
            }
        }
    }

    // epilogue: C/D layout col = lane&15, row = kg*4 + j
    #pragma unroll
    for (int fn = 0; fn < 4; ++fn) {
        int col = n0 + wn * 64 + fn * 16 + fr;
        float bv = bias[col];
        #pragma unroll
        for (int fm = 0; fm < FM; ++fm) {
            int rowb = m0 + wm * (FM * 16) + fm * 16 + kg * 4;
            #pragma unroll
            for (int j = 0; j < 4; ++j) {
                float v = fmaxf(acc[fm][fn][j] + bv, 0.f);
                size_t o = (size_t)(rowb + j) * ldc + col;
                if (epi) {
                    unsigned short h = f2bf(v);
                    Ch[o] = h;
                    Cl[o] = f2bf(v - bf2f(h));
                } else {
                    Cf[o] = v;
                }
            }
        }
    }
}

// ---------------- logits: out = h @ W2 + b2, K=512, N=9 ----------------
__global__ __launch_bounds__(256) void logits_kernel(
    const float* __restrict__ h, const float* __restrict__ W2,
    const float* __restrict__ b2, float* __restrict__ out)
{
    __shared__ float w2s[512 * NCc];
    for (int i = threadIdx.x; i < 512 * NCc; i += 256) w2s[i] = W2[i];
    __syncthreads();

    int wave = threadIdx.x >> 6, lane = threadIdx.x & 63;
    int row = blockIdx.x * 4 + wave;
    const float* hr = h + (size_t)row * 512;

    float p[NCc] = {};
    #pragma unroll
    for (int j = 0; j < 8; ++j) {
        int k = lane + 64 * j;
        float hv = hr[k];
        const float* wrow = &w2s[k * NCc];
        #pragma unroll
        for (int n = 0; n < NCc; ++n) p[n] += hv * wrow[n];
    }
    #pragma unroll
    for (int off = 32; off > 0; off >>= 1) {
        #pragma unroll
        for (int n = 0; n < NCc; ++n) p[n] += __shfl_down(p[n], off);
    }
    if (lane == 0) {
        float* orow = out + (size_t)row * NCc;
        #pragma unroll
        for (int n = 0; n < NCc; ++n) orow[n] = p[n] + b2[n];
    }
}

extern "C" void kernel_launch(void* const* d_in, const int* in_sizes, int n_in,
                              void* d_out, int out_size, void* d_ws, size_t ws_size,
                              hipStream_t stream)
{
    const float* seq   = (const float*)d_in[0];
    const float* feats = (const float*)d_in[1];
    const float* roi   = (const float*)d_in[2];
    const int*   bbox  = (const int*)d_in[3];
    const int*   amask = (const int*)d_in[4];
    const float* Wp = (const float*)d_in[5];
    const float* bp = (const float*)d_in[6];
    const float* Wf = (const float*)d_in[7];
    const float* bf = (const float*)d_in[8];
    const float* W1 = (const float*)d_in[9];
    const float* b1 = (const float*)d_in[10];
    const float* W2 = (const float*)d_in[11];
    const float* b2 = (const float*)d_in[12];
    float* out = (float*)d_out;

    char* ws = (char*)d_ws;
    unsigned short* A_hi  = (unsigned short*)(ws);
    unsigned short* A_lo  = (unsigned short*)(ws + 33554432);
    unsigned short* fu_hi = (unsigned short*)(ws + 67108864);
    unsigned short* fu_lo = (unsigned short*)(ws + 92274688);
    unsigned short* Bf_hi = (unsigned short*)(ws + 117440512);
    unsigned short* Bf_lo = (unsigned short*)(ws + 119013376);
    unsigned short* B1_hi = (unsigned short*)(ws + 120586240);
    unsigned short* B1_lo = (unsigned short*)(ws + 121372672);
    float*          Weq   = (float*)(ws + 122159104);
    float*          beq   = (float*)(ws + 122945536);
    float*          hbuf  = (float*)(ws);              // aliases A_hi/A_lo (dead after fuse)

    weq_beq_kernel<<<257, 768, 0, stream>>>(Wp, bp, Wf, bf, Weq, beq);
    pool_kernel<<<Bb * Rr, 256, 0, stream>>>(seq, roi, bbox, amask, feats, A_hi, A_lo);
    // Bf[768][1024] = [ Wf_t^T | Weq^T ]
    tconv_kernel<<<dim3(24, 24), 256, 0, stream>>>(Wf, 768, Bf_hi, Bf_lo, 1024, 0);
    tconv_kernel<<<dim3(8, 24), 256, 0, stream>>>(Weq, 768, Bf_hi, Bf_lo, 1024, 768);
    // B1[512][768] = W1^T
    tconv_kernel<<<dim3(24, 16), 256, 0, stream>>>(W1, 512, B1_hi, B1_lo, 768, 0);

    // fused = relu(A_cat @ B_cat + beq): BM=256, grid 3x64 = 192 (%8==0)
    gemm8p<8><<<dim3(768 / 256, 16384 / 256), 512, 0, stream>>>(
        A_hi, A_lo, 1024, Bf_hi, Bf_lo, 1024, 1024, beq, 1,
        fu_hi, fu_lo, nullptr, 768);
    // h = relu(fused @ W1 + b1): BM=128, grid 2x128 = 256 (%8==0, full chip)
    gemm8p<4><<<dim3(512 / 256, 16384 / 128), 512, 0, stream>>>(
        fu_hi, fu_lo, 768, B1_hi, B1_lo, 768, 768, b1, 0,
        nullptr, nullptr, hbuf, 512);

    logits_kernel<<<(Bb * Rr) / 4, 256, 0, stream>>>(hbuf, W2, b2, out);
}